// Round 5
// baseline (226.270 us; speedup 1.0000x reference)
//
#include <hip/hip_runtime.h>
#include <math.h>

#define VV 128000
#define NB 128
#define PP 2048
#define OO 256

#define S   8           // chunks per row
#define CH  16000       // VV/S tokens per chunk
#define CW  500         // CH/32 bitmask words
#define NT1 256
#define CAP 128         // survivor slots per chunk
#define HS1 512         // hash slots (count table)

#define NT2 256
#define MC  (S*CAP)     // 1024 merge slots

#define BIG_NEG_F (-1e30f)
#define PAD_KEY 0x007FFFFF80000000ULL  // packkey(-inf, 0x7fffffff)
#define LOG2E 1.4426950408889634f

__device__ __forceinline__ unsigned long long packkey(float f, int idx) {
  unsigned int b = __float_as_uint(f);
  unsigned int mf = (b & 0x80000000u) ? ~b : (b | 0x80000000u);
  return ((unsigned long long)mf << 32) | (unsigned long long)(unsigned int)(~(unsigned int)idx);
}
__device__ __forceinline__ float unpack_val(unsigned long long k) {
  unsigned int mf = (unsigned int)(k >> 32);
  unsigned int b = (mf & 0x80000000u) ? (mf & 0x7fffffffu) : ~mf;
  return __uint_as_float(b);
}
__device__ __forceinline__ int unpack_idx(unsigned long long k) {
  return (int)(~(unsigned int)(k & 0xffffffffu));
}
__device__ __forceinline__ float ulp_down(float f, int n) {
  unsigned int b = __float_as_uint(f);
  unsigned int m = (b & 0x80000000u) ? ~b : (b | 0x80000000u);
  m -= (unsigned int)n;
  unsigned int r = (m & 0x80000000u) ? (m & 0x7fffffffu) : ~m;
  return __uint_as_float(r);
}

// in-register descending bitonic sort of 64 values across a wave (lane0 = max)
__device__ __forceinline__ float wave_sort64_desc(float v, int lane) {
  for (int k = 2; k <= 64; k <<= 1) {
    for (int j = k >> 1; j > 0; j >>= 1) {
      float o = __shfl_xor(v, j, 64);
      bool smaller = (lane & j) == 0;
      bool dir = (lane & k) == 0;
      bool keepmax = (smaller == dir);
      v = keepmax ? fmaxf(v, o) : fminf(v, o);
    }
  }
  return v;
}

template <int N, int T>
__device__ __forceinline__ void bitonic_desc_u64(unsigned long long* a, int tid) {
  for (int k = 2; k <= N; k <<= 1) {
    for (int j = k >> 1; j > 0; j >>= 1) {
      for (int i = tid; i < N; i += T) {
        int ixj = i ^ j;
        if (ixj > i) {
          unsigned long long x = a[i], y = a[ixj];
          bool up = (i & k) == 0;
          if ((x < y) == up) { a[i] = y; a[ixj] = x; }
        }
      }
      __syncthreads();
    }
  }
}

// ---------------- kernel 1: per-chunk penalize + exp2-sum + survivor select --
__global__ __launch_bounds__(NT1)
void k1_select(const float* __restrict__ logits,
               const int* __restrict__ prompt_ids,
               const int* __restrict__ output_ids,
               const int* __restrict__ stop_ids,
               const int* __restrict__ min_tokens,
               const float* __restrict__ presence_p,
               const float* __restrict__ frequency_p,
               const float* __restrict__ repetition_p,
               const float* __restrict__ temperature,
               unsigned long long* __restrict__ ws_cand,
               float* __restrict__ ws_sum,
               int* __restrict__ ws_cnt)
{
#pragma clang fp contract(off)
  __shared__ unsigned int pbits[CW];
  __shared__ unsigned int obits[CW];
  __shared__ int hkey[HS1];
  __shared__ int hval[HS1];
  __shared__ float smax[NT1];
  __shared__ float wsum[NT1 / 64];
  __shared__ float tau_sh;
  __shared__ int cnt_sh;

  const int chunk = blockIdx.x;
  const int row   = blockIdx.y;
  const int tid   = threadIdx.x;
  const int lane  = tid & 63;
  const int base  = chunk * CH;

  const float fp  = frequency_p[row];
  const float pp  = presence_p[row];
  const float rp  = repetition_p[row];
  const float inv_rp = 1.0f / rp;          // approx mul path (phase A only)
  const float tmp = temperature[row];
  const float t   = (tmp < 1e-5f) ? 1.0f : tmp;
  const float c2  = LOG2E / t;             // exp(x/t) = exp2(x*c2)
  const bool need = min_tokens[row] > OO;
  const int s0 = stop_ids[row * 4 + 0];
  const int s1 = stop_ids[row * 4 + 1];
  const int s2 = stop_ids[row * 4 + 2];
  const int s3 = stop_ids[row * 4 + 3];
  const bool anystop = need &&
      (((unsigned)(s0 - base) < CH) || ((unsigned)(s1 - base) < CH) ||
       ((unsigned)(s2 - base) < CH) || ((unsigned)(s3 - base) < CH));

  // init LDS
  for (int i = tid; i < CW; i += NT1) { pbits[i] = 0u; obits[i] = 0u; }
  for (int i = tid; i < HS1; i += NT1) { hkey[i] = -1; hval[i] = 0; }
  if (tid == 0) cnt_sh = 0;
  __syncthreads();

  // prompt bitmask (chunk-local), int4 loads
  const int4* pr4 = (const int4*)(prompt_ids + (size_t)row * PP);
  for (int i = tid; i < PP / 4; i += NT1) {
    int4 tv = pr4[i];
    int l;
    l = tv.x - base; if ((unsigned)l < CH) atomicOr(&pbits[l >> 5], 1u << (l & 31));
    l = tv.y - base; if ((unsigned)l < CH) atomicOr(&pbits[l >> 5], 1u << (l & 31));
    l = tv.z - base; if ((unsigned)l < CH) atomicOr(&pbits[l >> 5], 1u << (l & 31));
    l = tv.w - base; if ((unsigned)l < CH) atomicOr(&pbits[l >> 5], 1u << (l & 31));
  }
  // output counts: flag bitmask + small hash
  for (int i = tid; i < OO; i += NT1) {
    int tok = output_ids[row * OO + i];
    int l = tok - base;
    if ((unsigned)l < CH) {
      atomicOr(&obits[l >> 5], 1u << (l & 31));
      unsigned int h = ((unsigned int)tok * 2654435761u) >> 23;
      for (;;) {
        int k = hkey[h];
        if (k == tok) { atomicAdd(&hval[h], 1); break; }
        if (k == -1) {
          int prev = atomicCAS(&hkey[h], -1, tok);
          if (prev == -1 || prev == tok) { atomicAdd(&hval[h], 1); break; }
          continue;
        }
        h = (h + 1) & (HS1 - 1);
      }
    }
  }
  __syncthreads();

  const float* __restrict__ lrow = logits + (size_t)row * VV + base;
  const int NIT = (CH + NT1 * 8 - 1) / (NT1 * 8);

  // ---- phase A: per-thread max + exp2 sum (approx penalty: mul not div) ----
  float mx = -INFINITY;
  float esum = 0.0f;
  for (int it = 0; it < NIT; ++it) {
    int li = (it * NT1 + tid) << 3;
    if (li < CH) {
      float4 xa = *(const float4*)(lrow + li);
      float4 xb = *(const float4*)(lrow + li + 4);
      unsigned int w  = (unsigned)li >> 5;
      unsigned int sh = (unsigned)li & 31u;
      unsigned int pm8 = (pbits[w] >> sh) & 255u;
      unsigned int om8 = (obits[w] >> sh) & 255u;
      float xs[8] = {xa.x, xa.y, xa.z, xa.w, xb.x, xb.y, xb.z, xb.w};
#pragma unroll
      for (int e = 0; e < 8; ++e) {
        float xp = xs[e];
        int v = base + li + e;
        if (anystop && ((v == s0) | (v == s1) | (v == s2) | (v == s3)))
          xp = BIG_NEG_F;
        if ((pm8 | om8) & (1u << e)) {
          xp = (xp > 0.0f) ? (xp * inv_rp) : (xp * rp);
          if ((om8 >> e) & 1u) {
            float cnt = 0.0f;
            unsigned int h = ((unsigned int)v * 2654435761u) >> 23;
            for (;;) {
              int k = hkey[h];
              if (k == -1) break;
              if (k == v) { cnt = (float)hval[h]; break; }
              h = (h + 1) & (HS1 - 1);
            }
            xp = xp - fp * cnt - pp;
          }
        }
        mx = fmaxf(mx, xp);
        esum += exp2f(xp * c2);
      }
    }
  }

  // wave reduce exp-sum
  float ss = esum;
#pragma unroll
  for (int off = 32; off > 0; off >>= 1) ss += __shfl_down(ss, off, 64);
  if (lane == 0) wsum[tid >> 6] = ss;

  // per-wave register sort of thread maxima -> 4 descending runs in LDS
  smax[tid] = wave_sort64_desc(mx, lane);
  __syncthreads();

  // thread 0: exact 64th-largest of the 256 maxima via 4-way merge
  if (tid == 0) {
    int p0 = 0, p1 = 0, p2 = 0, p3 = 0;
    float tau = -INFINITY;
    for (int n = 0; n < 64; ++n) {
      float v0 = (p0 < 64) ? smax[p0]       : -INFINITY;
      float v1 = (p1 < 64) ? smax[64 + p1]  : -INFINITY;
      float v2 = (p2 < 64) ? smax[128 + p2] : -INFINITY;
      float v3 = (p3 < 64) ? smax[192 + p3] : -INFINITY;
      float m01 = fmaxf(v0, v1), m23 = fmaxf(v2, v3);
      float m = fmaxf(m01, m23);
      if (m == v0) p0++;
      else if (m == v1) p1++;
      else if (m == v2) p2++;
      else p3++;
      tau = m;
    }
    tau_sh = ulp_down(tau, 16);   // slack covers mul-vs-div approx error
    ws_sum[row * S + chunk] = wsum[0] + wsum[1] + wsum[2] + wsum[3];
  }
  __syncthreads();
  const float taueff = tau_sh;

  // ---- phase B: re-stream (L2/L3-warm); raw-filter, exact recompute, append
  unsigned long long* __restrict__ wc = ws_cand + ((size_t)row * S + chunk) * CAP;
  for (int it = 0; it < NIT; ++it) {
    int li = (it * NT1 + tid) << 3;
    if (li < CH) {
      float4 xa = *(const float4*)(lrow + li);
      float4 xb = *(const float4*)(lrow + li + 4);
      float xs[8] = {xa.x, xa.y, xa.z, xa.w, xb.x, xb.y, xb.z, xb.w};
#pragma unroll
      for (int e = 0; e < 8; ++e) {
        float x = xs[e];
        if (x >= taueff) {   // raw >= penalized -> safe superset
          int v = base + li + e;
          int ll = li + e;
          if (anystop && ((v == s0) | (v == s1) | (v == s2) | (v == s3)))
            x = fminf(x, BIG_NEG_F);
          bool pm = (pbits[(unsigned)ll >> 5] >> ((unsigned)ll & 31u)) & 1u;
          bool om = (obits[(unsigned)ll >> 5] >> ((unsigned)ll & 31u)) & 1u;
          float cnt = 0.0f;
          if (om) {
            unsigned int h = ((unsigned int)v * 2654435761u) >> 23;
            for (;;) {
              int k = hkey[h];
              if (k == -1) break;
              if (k == v) { cnt = (float)hval[h]; break; }
              h = (h + 1) & (HS1 - 1);
            }
          }
          if (pm || om) x = (x > 0.0f) ? (x / rp) : (x * rp);
          x = x - fp * cnt;
          if (om) x = x - pp;
          float xd = x / t;               // exact reference finalist value
          int p = atomicAdd(&cnt_sh, 1);
          if (p < CAP) wc[p] = packkey(xd, v);
        }
      }
    }
  }
  __syncthreads();
  if (tid == 0) ws_cnt[row * S + chunk] = (cnt_sh < CAP) ? cnt_sh : CAP;
}

// ---------------- kernel 2: merge + finalize --------------------------------
__global__ __launch_bounds__(NT2)
void k2_finalize(const float* __restrict__ temperature,
                 const int* __restrict__ top_k,
                 const float* __restrict__ top_p,
                 const float* __restrict__ noise,
                 const unsigned long long* __restrict__ ws_cand,
                 const float* __restrict__ ws_sum,
                 const int* __restrict__ ws_cnt,
                 float* __restrict__ out, int K)
{
#pragma clang fp contract(off)
  __shared__ unsigned long long cand[MC];
  __shared__ int cnts[S];
  __shared__ float sv[64];
  __shared__ int   si[64];
  __shared__ float se[64];
  __shared__ float gv[64];

  const int row = blockIdx.x;
  const int tid = threadIdx.x;

  const float tmp = temperature[row];
  const float t   = (tmp < 1e-5f) ? 1.0f : tmp;
  const int   tk  = top_k[row];
  const float tpv = top_p[row];

  if (tid < S) cnts[tid] = ws_cnt[row * S + tid];
  __syncthreads();

  for (int g = tid; g < MC; g += NT2) {
    int c = g >> 7;            // / CAP
    int i = g & (CAP - 1);
    cand[g] = (i < cnts[c]) ? ws_cand[((size_t)row * S + c) * CAP + i] : PAD_KEY;
  }
  __syncthreads();

  bitonic_desc_u64<MC, NT2>(cand, tid);

  if (tid < 64) {
    unsigned long long kk = cand[tid];
    float val = unpack_val(kk);
    int   idx = unpack_idx(kk);
    float m = unpack_val(cand[0]);
    sv[tid] = val;
    si[tid] = idx;
    bool ok = (unsigned)idx < VV;
    float u = ok ? noise[(size_t)row * VV + idx] : 0.5f;
    float g = -logf(-logf(u));
    se[tid] = expf(val - m);
    gv[tid] = val / t + g;
  }
  __syncthreads();

  if (tid == 0) {
    float Ssum = 0.0f;
    for (int c = 0; c < S; c++) Ssum += ws_sum[row * S + c];
    const float m = sv[0];
    const float Z = Ssum * exp2f(-m * LOG2E);   // full-row softmax denominator

    int keff = (tk < 1) ? 64 : (tk < 64 ? tk : 64);

    float cum = 0.0f;
    int nk = 0;
    for (int j = 0; j < 64; j++) {
      if (j >= keff) break;
      if (!(cum < tpv)) break;
      nk++;
      cum += se[j] / Z;
    }

    float Zk = 0.0f;
    for (int j = 0; j < nk; j++) Zk += se[j];
    const float logZk = logf(Zk);

    float bv = -INFINITY; int bi = 0x7fffffff;
    for (int j = 0; j < nk; j++) {
      float val = gv[j];
      if (val > bv || (val == bv && si[j] < bi)) { bv = val; bi = si[j]; }
    }
    const int samp = (tmp < 1e-5f) ? si[0] : bi;
    out[row] = (float)samp;

    unsigned long long bm0 = 0ull, bm1 = 0ull;
    for (int j = 0; j < nk; j++) {
      int ix = si[j];
      if (ix < 64) bm0 |= 1ull << ix;
      else if (ix < 128) bm1 |= 1ull << (ix - 64);
    }
    int fi = 0;
    for (int j = 0; j < K; j++) {
      float lp; int ix;
      if (j < nk) {
        lp = (sv[j] - m) - logZk;
        ix = si[j];
      } else {
        while ((fi < 64) ? ((bm0 >> fi) & 1ull) : ((bm1 >> (fi - 64)) & 1ull)) fi++;
        ix = fi; fi++;
        lp = BIG_NEG_F;
      }
      out[NB + row * K + j]            = lp;
      out[NB + NB * K + row * K + j]   = (float)ix;
    }
  }
}

extern "C" void kernel_launch(void* const* d_in, const int* in_sizes, int n_in,
                              void* d_out, int out_size, void* d_ws, size_t ws_size,
                              hipStream_t stream) {
  const float* logits = (const float*)d_in[0];
  const int*   prompt = (const int*)d_in[1];
  const int*   outids = (const int*)d_in[2];
  const int*   stop   = (const int*)d_in[3];
  const int*   mint   = (const int*)d_in[4];
  const float* pres   = (const float*)d_in[5];
  const float* freq   = (const float*)d_in[6];
  const float* rep    = (const float*)d_in[7];
  const float* temp   = (const float*)d_in[8];
  const int*   topk   = (const int*)d_in[9];
  const float* topp   = (const float*)d_in[10];
  const float* noise  = (const float*)d_in[11];

  int B_ = in_sizes[4];                     // 128
  int K_ = (out_size - B_) / (2 * B_);      // 20

  unsigned long long* ws_cand = (unsigned long long*)d_ws;       // NB*S*CAP u64
  float* ws_sum = (float*)(ws_cand + (size_t)NB * S * CAP);      // NB*S f32
  int*   ws_cnt = (int*)(ws_sum + (size_t)NB * S);               // NB*S i32

  dim3 g1(S, B_);
  k1_select<<<g1, NT1, 0, stream>>>(logits, prompt, outids, stop, mint,
                                    pres, freq, rep, temp,
                                    ws_cand, ws_sum, ws_cnt);
  k2_finalize<<<B_, NT2, 0, stream>>>(temp, topk, topp, noise,
                                      ws_cand, ws_sum, ws_cnt,
                                      (float*)d_out, K_);
}